// Round 9
// baseline (450.117 us; speedup 1.0000x reference)
//
#include <hip/hip_runtime.h>
#include <hip/hip_fp16.h>

#define K_FEATS 128
#define RBSHIFT 9
#define RB 512        // fine-bucket node range (pow2); NB = ceil(n/512) <= 256

typedef short bf16x8 __attribute__((ext_vector_type(8)));
typedef float f32x4 __attribute__((ext_vector_type(4)));

__device__ __forceinline__ unsigned short bf16_rne(float x) {
    unsigned u = __float_as_uint(x);
    unsigned r = (u + 0x7FFFu + ((u >> 16) & 1u)) >> 16;
    return (unsigned short)r;
}
__device__ __forceinline__ float bf16_f(unsigned short h) {
    return __uint_as_float(((unsigned)h) << 16);
}

// ------- K1: coarse count (both keys) + W transpose/split, one dispatch -----
__global__ __launch_bounds__(256) void count_split(
    const int* __restrict__ src, const int* __restrict__ dst,
    int* __restrict__ partialS, int* __restrict__ partialD,
    const float* __restrict__ W0, const float* __restrict__ W1,
    const float* __restrict__ W2,
    unsigned short* __restrict__ W0th, unsigned short* __restrict__ W0tl,
    unsigned short* __restrict__ W1th, unsigned short* __restrict__ W1tl,
    unsigned short* __restrict__ W2th, unsigned short* __restrict__ W2tl,
    int ne, int chunkA, int C, int NB)
{
    __shared__ int hS[256];
    __shared__ int hD[256];
    int bid = blockIdx.x, t = threadIdx.x;
    if (bid < C) {
        if (t < NB) { hS[t] = 0; hD[t] = 0; }
        __syncthreads();
        int e0 = bid * chunkA, e1 = min(ne, e0 + chunkA);
        for (int e = e0 + t; e < e1; e += 256) {
            atomicAdd(&hS[src[e] >> RBSHIFT], 1);
            atomicAdd(&hD[dst[e] >> RBSHIFT], 1);
        }
        __syncthreads();
        for (int i = t; i < NB; i += 256) {
            partialS[i * C + bid] = hS[i];
            partialD[i * C + bid] = hD[i];
        }
    } else {
        int e = (bid - C) * 256 + t;
        const float* W; unsigned short *Wh, *Wl; int NC, idx;
        bool ok = true;
        if (e < 16384)      { W = W0; Wh = W0th; Wl = W0tl; NC = 128; idx = e; }
        else if (e < 32768) { W = W1; Wh = W1th; Wl = W1tl; NC = 128; idx = e - 16384; }
        else if (e < 40960) { W = W2; Wh = W2th; Wl = W2tl; NC = 64;  idx = e - 32768; }
        else ok = false;
        if (ok) {
            int c = idx >> 7, kk = idx & 127;
            float w = W[kk * NC + c];
            unsigned short h = bf16_rne(w);
            Wh[idx] = h;
            Wl[idx] = bf16_rne(w - bf16_f(h));
        }
    }
}

// ------- K2: per-bucket prefix over chunks ---------------------------------
__global__ __launch_bounds__(256) void bucket_prefix(
    int* __restrict__ partialS, int* __restrict__ partialD,
    int* __restrict__ totS, int* __restrict__ totD, int C, int NB)
{
    __shared__ int sh[256];
    int b = blockIdx.x, t = threadIdx.x;
    int* part = blockIdx.y ? partialD : partialS;
    int* tot = blockIdx.y ? totD : totS;
    int v = (t < C) ? part[b * C + t] : 0;
    sh[t] = v;
    __syncthreads();
    for (int off = 1; off < 256; off <<= 1) {
        int x = (t >= off) ? sh[t - off] : 0;
        __syncthreads();
        sh[t] += x;
        __syncthreads();
    }
    if (t < C) part[b * C + t] = sh[t] - v;
    if (t == 255) tot[b] = sh[255];
}

// ------- K3: coarse scatter; bucket offsets re-derived via LDS scan --------
__global__ __launch_bounds__(256) void bucket_scatter(
    const int* __restrict__ src, const int* __restrict__ dst,
    const int* __restrict__ partialS, const int* __restrict__ partialD,
    const int* __restrict__ totS, const int* __restrict__ totD,
    unsigned short* __restrict__ src_bkt, int* __restrict__ edge_bkt,
    int ne, int chunkA, int C, int NB)
{
    __shared__ int shB[256];
    __shared__ int curS[256];
    __shared__ int curD[256];
    int bid = blockIdx.x, t = threadIdx.x;
    int vS = (t < NB) ? totS[t] : 0;
    shB[t] = vS;
    __syncthreads();
    for (int off = 1; off < 256; off <<= 1) {
        int x = (t >= off) ? shB[t - off] : 0;
        __syncthreads();
        shB[t] += x;
        __syncthreads();
    }
    if (t < NB) curS[t] = (shB[t] - vS) + partialS[t * C + bid];
    __syncthreads();
    int vD = (t < NB) ? totD[t] : 0;
    shB[t] = vD;
    __syncthreads();
    for (int off = 1; off < 256; off <<= 1) {
        int x = (t >= off) ? shB[t - off] : 0;
        __syncthreads();
        shB[t] += x;
        __syncthreads();
    }
    if (t < NB) curD[t] = (shB[t] - vD) + partialD[t * C + bid];
    __syncthreads();
    int e0 = bid * chunkA, e1 = min(ne, e0 + chunkA);
    for (int e = e0 + t; e < e1; e += 256) {
        int s = src[e];
        int d = dst[e];
        int posD = atomicAdd(&curD[d >> RBSHIFT], 1);
        edge_bkt[posD] = ((d & (RB - 1)) << 17) | s;
        int posS = atomicAdd(&curS[s >> RBSHIFT], 1);
        src_bkt[posS] = (unsigned short)(s & (RB - 1));
    }
}

// ------- K4: fine pass; bucket offsets re-derived via LDS scan --------------
// bid even (y=0): dst — hist+scan -> row_off/norm_dst + csr scatter
// bid odd  (y=1): src — hist -> norm_src
__global__ __launch_bounds__(256) void fine_all(
    const int* __restrict__ edge_bkt, const unsigned short* __restrict__ src_bkt,
    const int* __restrict__ totS, const int* __restrict__ totD,
    int* __restrict__ row_off, float* __restrict__ norm_dst,
    float* __restrict__ norm_src, int* __restrict__ csr, int n, int ne, int NB)
{
    __shared__ int shA[RB];     // hist + cursors
    __shared__ int shB[256];    // scans
    int bid = blockIdx.x, t = threadIdx.x;
    int y = bid & 1, b = bid >> 1;
    const int* tot = y ? totS : totD;
    int v = (t < NB) ? tot[t] : 0;
    shB[t] = v;
    __syncthreads();
    for (int off = 1; off < 256; off <<= 1) {
        int x = (t >= off) ? shB[t - off] : 0;
        __syncthreads();
        shB[t] += x;
        __syncthreads();
    }
    int e1 = shB[b];           // inclusive scan at b = exclusive end
    int ebase = e1 - tot[b];   // exclusive start
    __syncthreads();
    int lo = b << RBSHIFT;
    for (int i = t; i < RB; i += 256) shA[i] = 0;
    __syncthreads();
    if (y == 1) {
        for (int e = ebase + t; e < e1; e += 256)
            atomicAdd(&shA[src_bkt[e]], 1);
        __syncthreads();
        for (int i = t; i < RB; i += 256) {
            int g = lo + i;
            if (g < n) norm_src[g] = rsqrtf((float)max(shA[i], 1));
        }
        return;
    }
    if (bid == 0 && t == 0) row_off[n] = ne;
    for (int e = ebase + t; e < e1; e += 256)
        atomicAdd(&shA[(unsigned)edge_bkt[e] >> 17], 1);
    __syncthreads();
    int v0 = shA[2 * t], v1 = shA[2 * t + 1];
    shB[t] = v0 + v1;
    __syncthreads();
    for (int off = 1; off < 256; off <<= 1) {
        int x = (t >= off) ? shB[t - off] : 0;
        __syncthreads();
        shB[t] += x;
        __syncthreads();
    }
    int excl = shB[t] - (v0 + v1) + ebase;
    int g0 = lo + 2 * t, g1 = g0 + 1;
    if (g0 < n) { row_off[g0] = excl;      norm_dst[g0] = rsqrtf((float)max(v0, 1)); }
    if (g1 < n) { row_off[g1] = excl + v0; norm_dst[g1] = rsqrtf((float)max(v1, 1)); }
    shA[2 * t] = excl;          // cursors
    shA[2 * t + 1] = excl + v0;
    __syncthreads();
    for (int e = ebase + t; e < e1; e += 256) {
        int p = edge_bkt[e];
        int pos = atomicAdd(&shA[(unsigned)p >> 17], 1);
        csr[pos] = p & 0x1FFFF;
    }
}

// ---------------- MFMA GEMM: out = scale ⊙ (X @ W), bf16 hi/lo split --------
// Output T is COLUMN-SLICED: slice s = 16 consecutive features, stored at
// Th[s*SS + row*16 + c] (SS = n_pad*16 halfs). Slice -> XCD residency in the
// aggregation kernels. MODE 1 reads the same sliced layout.
// MODE 0: Xf fp32 [n][128] row-major (input features), trunc-hi split.
// MODE 1: X16 fp16 sliced (exact trunc split; fp16 residual exact in bf16).
template <int NCOL, bool HALF_OUT, int MODE>
__global__ __launch_bounds__(256) void gemm_mfma(
    const __half* __restrict__ X16, const float* __restrict__ Xf,
    const unsigned short* __restrict__ Wth, const unsigned short* __restrict__ Wtl,
    const float* __restrict__ scale, void* __restrict__ outv, int n, int SS)
{
    constexpr int CT = NCOL / 16;
    constexpr int CHUNKS = NCOL * 16;          // 16B chunks per half
    __shared__ unsigned short Ws[16 * NCOL * 8];  // [sec][col^(sec&7)][8]

    int t = threadIdx.x;
    int w = t >> 6, lane = t & 63, m = lane & 15, q = lane >> 4;
    int r0 = blockIdx.x * 128 + w * 32;

    f32x4 acc[2][CT];
#pragma unroll
    for (int i = 0; i < 2; i++)
#pragma unroll
        for (int j = 0; j < CT; j++) acc[i][j] = (f32x4){0.f, 0.f, 0.f, 0.f};

    // all A fragments up front, split in-register (trunc-hi / exact-residual)
    bf16x8 ah[2][4], al[2][4];
#pragma unroll
    for (int rt = 0; rt < 2; rt++) {
        int row = r0 + rt * 16 + m;
#pragma unroll
        for (int k = 0; k < 4; k++) {
            float f[8];
            if (MODE == 0) {
                size_t base = (size_t)row * K_FEATS + q * 8;
                if (row < n) {
                    *(float4*)&f[0] = *(const float4*)(Xf + base + k * 32);
                    *(float4*)&f[4] = *(const float4*)(Xf + base + k * 32 + 4);
                } else {
#pragma unroll
                    for (int j = 0; j < 8; j++) f[j] = 0.f;
                }
            } else {
                // cols k*32+q*8 .. +8 live in slice 2k+(q>>1), offset (q&1)*8
                size_t abase = (size_t)(2 * k + (q >> 1)) * SS +
                               (size_t)row * 16 + (q & 1) * 8;
                union { uint4 q4; __half h[8]; } U;
                U.q4 = *(const uint4*)(X16 + abase);
#pragma unroll
                for (int j = 0; j < 8; j++) f[j] = __half2float(U.h[j]);
            }
            union { bf16x8 v; unsigned short u[8]; } H, L;
#pragma unroll
            for (int j = 0; j < 8; j++) {
                unsigned uf = __float_as_uint(f[j]);
                H.u[j] = (unsigned short)(uf >> 16);                 // trunc hi
                float r = f[j] - __uint_as_float(uf & 0xFFFF0000u);  // exact
                if (MODE == 1)
                    L.u[j] = (unsigned short)(__float_as_uint(r) >> 16); // exact
                else
                    L.u[j] = bf16_rne(r);
            }
            ah[rt][k] = H.v;
            al[rt][k] = L.v;
        }
    }

    // stage W-hi
#pragma unroll
    for (int i = 0; i < CHUNKS / 256; i++) {
        int g = t + i * 256;
        int col = g >> 4, sec = g & 15;
        *(bf16x8*)(Ws + sec * NCOL * 8 + ((col ^ (sec & 7)) * 8)) =
            *(const bf16x8*)(Wth + g * 8);
    }
    __syncthreads();
    // phase 1: a_h*b_h + a_l*b_h
#pragma unroll
    for (int k = 0; k < 4; k++) {
        int sec = k * 4 + q;
#pragma unroll
        for (int ct = 0; ct < CT; ct++) {
            bf16x8 bh = *(const bf16x8*)(Ws + sec * NCOL * 8 +
                                         (((ct * 16 + m) ^ (sec & 7)) * 8));
            acc[0][ct] = __builtin_amdgcn_mfma_f32_16x16x32_bf16(ah[0][k], bh, acc[0][ct], 0, 0, 0);
            acc[0][ct] = __builtin_amdgcn_mfma_f32_16x16x32_bf16(al[0][k], bh, acc[0][ct], 0, 0, 0);
            acc[1][ct] = __builtin_amdgcn_mfma_f32_16x16x32_bf16(ah[1][k], bh, acc[1][ct], 0, 0, 0);
            acc[1][ct] = __builtin_amdgcn_mfma_f32_16x16x32_bf16(al[1][k], bh, acc[1][ct], 0, 0, 0);
        }
    }
    __syncthreads();
    // stage W-lo
#pragma unroll
    for (int i = 0; i < CHUNKS / 256; i++) {
        int g = t + i * 256;
        int col = g >> 4, sec = g & 15;
        *(bf16x8*)(Ws + sec * NCOL * 8 + ((col ^ (sec & 7)) * 8)) =
            *(const bf16x8*)(Wtl + g * 8);
    }
    __syncthreads();
    // phase 2: a_h*b_l
#pragma unroll
    for (int k = 0; k < 4; k++) {
        int sec = k * 4 + q;
#pragma unroll
        for (int ct = 0; ct < CT; ct++) {
            bf16x8 bl = *(const bf16x8*)(Ws + sec * NCOL * 8 +
                                         (((ct * 16 + m) ^ (sec & 7)) * 8));
            acc[0][ct] = __builtin_amdgcn_mfma_f32_16x16x32_bf16(ah[0][k], bl, acc[0][ct], 0, 0, 0);
            acc[1][ct] = __builtin_amdgcn_mfma_f32_16x16x32_bf16(ah[1][k], bl, acc[1][ct], 0, 0, 0);
        }
    }

    // sliced write: slice = ct, within-slice col = m
#pragma unroll
    for (int rt = 0; rt < 2; rt++) {
        int rb = r0 + rt * 16 + q * 4;
#pragma unroll
        for (int reg = 0; reg < 4; reg++) {
            int row = rb + reg;
            if (row < n) {
                float s = scale[row];
#pragma unroll
                for (int ct = 0; ct < CT; ct++) {
                    float v = acc[rt][ct][reg] * s;
                    size_t o = (size_t)ct * SS + (size_t)row * 16 + m;
                    if (HALF_OUT) ((__half*)outv)[o] = __float2half(v);
                    else ((float*)outv)[o] = v;
                }
            }
        }
    }
}

// ------- sliced aggregation (128 feats = 8 slices x 16) ---------------------
// slice = blockIdx%8 -> XCD residency (slice = 3.2MB, fits 4MiB L2).
// 4-lane teams, 4 fp16 feats/lane (8B), 4 edges in flight.
template <bool RELU>
__global__ __launch_bounds__(256) void aggregate4s(
    const __half* __restrict__ Tm, const int* __restrict__ row_off,
    const int* __restrict__ csr, const float* __restrict__ ndst,
    const float* __restrict__ bias, __half* __restrict__ Oh, int n, int SS)
{
    int lane = threadIdx.x & 3;
    int team = threadIdx.x >> 2;           // 64 teams/block
    int s = blockIdx.x & 7;                // slice == XCD residue
    int ch = blockIdx.x >> 3;
    int nch = gridDim.x >> 3;
    const __half* Ts = Tm + (size_t)s * SS + lane * 4;
    __half* Os = Oh + (size_t)s * SS + lane * 4;
    float b[4];
    *(float4*)b = *(const float4*)(bias + s * 16 + lane * 4);
    int stride = nch * 64;
    for (int v = ch * 64 + team; v < n; v += stride) {
        int i = row_off[v], e = row_off[v + 1];
        float nd = ndst[v];
        float a[4] = {};
        for (; i + 4 <= e; i += 4) {
            int u0 = csr[i], u1 = csr[i + 1], u2 = csr[i + 2], u3 = csr[i + 3];
            union { uint2 q; __half h[4]; } A, B, C, D;
            A.q = *(const uint2*)(Ts + (size_t)u0 * 16);
            B.q = *(const uint2*)(Ts + (size_t)u1 * 16);
            C.q = *(const uint2*)(Ts + (size_t)u2 * 16);
            D.q = *(const uint2*)(Ts + (size_t)u3 * 16);
#pragma unroll
            for (int j = 0; j < 4; j++)
                a[j] += (__half2float(A.h[j]) + __half2float(B.h[j])) +
                        (__half2float(C.h[j]) + __half2float(D.h[j]));
        }
        for (; i < e; i++) {
            union { uint2 q; __half h[4]; } A;
            A.q = *(const uint2*)(Ts + (size_t)csr[i] * 16);
#pragma unroll
            for (int j = 0; j < 4; j++) a[j] += __half2float(A.h[j]);
        }
        union { uint2 q; __half h[4]; } O;
#pragma unroll
        for (int j = 0; j < 4; j++) {
            float o = nd * a[j] + b[j];
            if (RELU) o = fmaxf(o, 0.f);
            O.h[j] = __float2half(o);
        }
        *(uint2*)(Os + (size_t)v * 16) = O.q;
    }
}

// ------- final sliced aggregation (64 feats = 4 slices x 16), fp32 out ------
// slice s = (bid&7)>>1: two XCD residues per slice; fp32 row-major output.
__global__ __launch_bounds__(256) void aggregate2s(
    const __half* __restrict__ Tm, const int* __restrict__ row_off,
    const int* __restrict__ csr, const float* __restrict__ ndst,
    const float* __restrict__ bias, float* __restrict__ out, int n, int SS)
{
    int lane = threadIdx.x & 3;
    int team = threadIdx.x >> 2;           // 64 teams/block
    int r = blockIdx.x & 7;
    int s = r >> 1;                        // slice 0..3
    int ch = (blockIdx.x >> 3) * 2 + (r & 1);
    int nch = (gridDim.x >> 3) * 2;
    const __half* Ts = Tm + (size_t)s * SS + lane * 4;
    float b[4];
    *(float4*)b = *(const float4*)(bias + s * 16 + lane * 4);
    int stride = nch * 64;
    for (int v = ch * 64 + team; v < n; v += stride) {
        int i = row_off[v], e = row_off[v + 1];
        float nd = ndst[v];
        float a[4] = {};
        for (; i + 4 <= e; i += 4) {
            int u0 = csr[i], u1 = csr[i + 1], u2 = csr[i + 2], u3 = csr[i + 3];
            union { uint2 q; __half h[4]; } A, B, C, D;
            A.q = *(const uint2*)(Ts + (size_t)u0 * 16);
            B.q = *(const uint2*)(Ts + (size_t)u1 * 16);
            C.q = *(const uint2*)(Ts + (size_t)u2 * 16);
            D.q = *(const uint2*)(Ts + (size_t)u3 * 16);
#pragma unroll
            for (int j = 0; j < 4; j++)
                a[j] += (__half2float(A.h[j]) + __half2float(B.h[j])) +
                        (__half2float(C.h[j]) + __half2float(D.h[j]));
        }
        for (; i < e; i++) {
            union { uint2 q; __half h[4]; } A;
            A.q = *(const uint2*)(Ts + (size_t)csr[i] * 16);
#pragma unroll
            for (int j = 0; j < 4; j++) a[j] += __half2float(A.h[j]);
        }
        float o[4];
#pragma unroll
        for (int j = 0; j < 4; j++) o[j] = nd * a[j] + b[j];
        *(float4*)(out + (size_t)v * 64 + s * 16 + lane * 4) = *(float4*)o;
    }
}

// ---------------- launch ----------------
extern "C" void kernel_launch(void* const* d_in, const int* in_sizes, int n_in,
                              void* d_out, int out_size, void* d_ws, size_t ws_size,
                              hipStream_t stream)
{
    const float* features = (const float*)d_in[0];
    const int* src = (const int*)d_in[1];
    const int* dst = (const int*)d_in[2];
    const float* W0 = (const float*)d_in[3];
    const float* b0 = (const float*)d_in[4];
    const float* W1 = (const float*)d_in[5];
    const float* b1 = (const float*)d_in[6];
    const float* W2 = (const float*)d_in[7];
    const float* b2 = (const float*)d_in[8];

    int n = in_sizes[0] / K_FEATS;  // 100000
    int ne = in_sizes[1];           // 1600000
    int n_pad = (n + 127) & ~127;   // 100096
    int SS = n_pad * 16;            // slice stride (halfs)

    char* ws = (char*)d_ws;
    size_t off = 0;
    auto take = [&](size_t bytes) -> char* {
        char* p = ws + off;
        off = (off + bytes + 255) & ~(size_t)255;
        return p;
    };
    __half* Xbuf = (__half*)take((size_t)n_pad * 128 * 2);  // h (fp16, sliced) ping
    __half* Th = (__half*)take((size_t)n_pad * 128 * 2);    // T (fp16, sliced) pong
    int* csr = (int*)take((size_t)ne * 4);
    int* edge_bkt = (int*)take((size_t)ne * 4);
    unsigned short* src_bkt = (unsigned short*)take((size_t)ne * 2);
    int* row_off = (int*)take((size_t)(n + 1) * 4);
    float* norm_src = (float*)take((size_t)n * 4);
    float* norm_dst = (float*)take((size_t)n * 4);
    unsigned short* W0th = (unsigned short*)take(128 * 128 * 2);
    unsigned short* W0tl = (unsigned short*)take(128 * 128 * 2);
    unsigned short* W1th = (unsigned short*)take(128 * 128 * 2);
    unsigned short* W1tl = (unsigned short*)take(128 * 128 * 2);
    unsigned short* W2th = (unsigned short*)take(64 * 128 * 2);
    unsigned short* W2tl = (unsigned short*)take(64 * 128 * 2);

    int NB = (n + RB - 1) >> RBSHIFT;        // 196 (must be <= 256)
    int chunkA = 8192;
    int C = (ne + chunkA - 1) / chunkA;
    if (C > 256) { chunkA = (ne + 255) / 256; C = (ne + chunkA - 1) / chunkA; }

    int* partialS = (int*)take((size_t)NB * C * 4);
    int* partialD = (int*)take((size_t)NB * C * 4);
    int* totS = (int*)take((size_t)NB * 4);
    int* totD = (int*)take((size_t)NB * 4);

    // CSR build: 4 dispatches (count+Wsplit, prefix, scatter, fine)
    count_split<<<C + 160, 256, 0, stream>>>(
        src, dst, partialS, partialD,
        W0, W1, W2, W0th, W0tl, W1th, W1tl, W2th, W2tl,
        ne, chunkA, C, NB);
    bucket_prefix<<<dim3(NB, 2), 256, 0, stream>>>(partialS, partialD, totS, totD, C, NB);
    bucket_scatter<<<C, 256, 0, stream>>>(src, dst, partialS, partialD,
                                          totS, totD, src_bkt, edge_bkt,
                                          ne, chunkA, C, NB);
    fine_all<<<2 * NB, 256, 0, stream>>>(edge_bkt, src_bkt, totS, totD,
                                         row_off, norm_dst, norm_src, csr,
                                         n, ne, NB);

    int gblocks = n_pad / 128;
    int agg_blocks = 2048;   // 8 slices x 256 chunks; 8 blocks/CU, max waves

    // layer 0 (fp32 features row-major in; sliced out) -> Th -> Xbuf
    gemm_mfma<128, true, 0><<<gblocks, 256, 0, stream>>>(
        nullptr, features, W0th, W0tl, norm_src, Th, n, SS);
    aggregate4s<true><<<agg_blocks, 256, 0, stream>>>(Th, row_off, csr, norm_dst,
                                                      b0, Xbuf, n, SS);
    // layer 1 (sliced fp16 in, exact trunc split; sliced out)
    gemm_mfma<128, true, 1><<<gblocks, 256, 0, stream>>>(
        Xbuf, nullptr, W1th, W1tl, norm_src, Th, n, SS);
    aggregate4s<true><<<agg_blocks, 256, 0, stream>>>(Th, row_off, csr, norm_dst,
                                                      b1, Xbuf, n, SS);
    // layer 2 (NCOL=64: 4 slices x 16; sliced fp16 T out)
    gemm_mfma<64, true, 1><<<gblocks, 256, 0, stream>>>(
        Xbuf, nullptr, W2th, W2tl, norm_src, Th, n, SS);
    aggregate2s<<<agg_blocks, 256, 0, stream>>>(Th, row_off, csr, norm_dst, b2,
                                                (float*)d_out, n, SS);
}

// Round 10
// 371.947 us; speedup vs baseline: 1.2102x; 1.2102x over previous
//
#include <hip/hip_runtime.h>
#include <hip/hip_fp16.h>

#define K_FEATS 128
#define RBSHIFT 9
#define RB 512        // fine-bucket node range (pow2); NB = ceil(n/512) <= 256

typedef short bf16x8 __attribute__((ext_vector_type(8)));
typedef float f32x4 __attribute__((ext_vector_type(4)));

__device__ __forceinline__ unsigned short bf16_rne(float x) {
    unsigned u = __float_as_uint(x);
    unsigned r = (u + 0x7FFFu + ((u >> 16) & 1u)) >> 16;
    return (unsigned short)r;
}
__device__ __forceinline__ float bf16_f(unsigned short h) {
    return __uint_as_float(((unsigned)h) << 16);
}

// ---- fused layer-0 GEMM block: T0 = X @ W0 (fp16 out, NO norm_src scale; ----
// ---- the scale moves into aggregate4h as an fma). Called as tail-blocks  ----
// ---- of the CSR dispatches to overlap with the underfilled CSR chain.    ----
__device__ __forceinline__ void gemm0_block(
    int gb, const float* __restrict__ Xf,
    const unsigned short* __restrict__ Wth, const unsigned short* __restrict__ Wtl,
    __half* __restrict__ outp, int n)
{
    __shared__ unsigned short Ws[16 * 128 * 8];   // 32KB, [sec][col^(sec&7)][8]
    int t = threadIdx.x;
    int w = t >> 6, lane = t & 63, m = lane & 15, q = lane >> 4;
    int r0 = gb * 128 + w * 32;

    f32x4 acc[2][8];
#pragma unroll
    for (int i = 0; i < 2; i++)
#pragma unroll
        for (int j = 0; j < 8; j++) acc[i][j] = (f32x4){0.f, 0.f, 0.f, 0.f};

    bf16x8 ah[2][4], al[2][4];
#pragma unroll
    for (int rt = 0; rt < 2; rt++) {
        int row = r0 + rt * 16 + m;
        size_t base = (size_t)row * K_FEATS + q * 8;
#pragma unroll
        for (int k = 0; k < 4; k++) {
            float f[8];
            if (row < n) {
                *(float4*)&f[0] = *(const float4*)(Xf + base + k * 32);
                *(float4*)&f[4] = *(const float4*)(Xf + base + k * 32 + 4);
            } else {
#pragma unroll
                for (int j = 0; j < 8; j++) f[j] = 0.f;
            }
            union { bf16x8 v; unsigned short u[8]; } H, L;
#pragma unroll
            for (int j = 0; j < 8; j++) {
                unsigned uf = __float_as_uint(f[j]);
                H.u[j] = (unsigned short)(uf >> 16);                 // trunc hi
                float r = f[j] - __uint_as_float(uf & 0xFFFF0000u);  // exact
                L.u[j] = bf16_rne(r);
            }
            ah[rt][k] = H.v;
            al[rt][k] = L.v;
        }
    }

#pragma unroll
    for (int i = 0; i < 8; i++) {                 // stage W-hi (2048 chunks)
        int g = t + i * 256;
        int col = g >> 4, sec = g & 15;
        *(bf16x8*)(Ws + sec * 128 * 8 + ((col ^ (sec & 7)) * 8)) =
            *(const bf16x8*)(Wth + g * 8);
    }
    __syncthreads();
#pragma unroll
    for (int k = 0; k < 4; k++) {
        int sec = k * 4 + q;
#pragma unroll
        for (int ct = 0; ct < 8; ct++) {
            bf16x8 bh = *(const bf16x8*)(Ws + sec * 128 * 8 +
                                         (((ct * 16 + m) ^ (sec & 7)) * 8));
            acc[0][ct] = __builtin_amdgcn_mfma_f32_16x16x32_bf16(ah[0][k], bh, acc[0][ct], 0, 0, 0);
            acc[0][ct] = __builtin_amdgcn_mfma_f32_16x16x32_bf16(al[0][k], bh, acc[0][ct], 0, 0, 0);
            acc[1][ct] = __builtin_amdgcn_mfma_f32_16x16x32_bf16(ah[1][k], bh, acc[1][ct], 0, 0, 0);
            acc[1][ct] = __builtin_amdgcn_mfma_f32_16x16x32_bf16(al[1][k], bh, acc[1][ct], 0, 0, 0);
        }
    }
    __syncthreads();
#pragma unroll
    for (int i = 0; i < 8; i++) {                 // stage W-lo
        int g = t + i * 256;
        int col = g >> 4, sec = g & 15;
        *(bf16x8*)(Ws + sec * 128 * 8 + ((col ^ (sec & 7)) * 8)) =
            *(const bf16x8*)(Wtl + g * 8);
    }
    __syncthreads();
#pragma unroll
    for (int k = 0; k < 4; k++) {
        int sec = k * 4 + q;
#pragma unroll
        for (int ct = 0; ct < 8; ct++) {
            bf16x8 bl = *(const bf16x8*)(Ws + sec * 128 * 8 +
                                         (((ct * 16 + m) ^ (sec & 7)) * 8));
            acc[0][ct] = __builtin_amdgcn_mfma_f32_16x16x32_bf16(ah[0][k], bl, acc[0][ct], 0, 0, 0);
            acc[1][ct] = __builtin_amdgcn_mfma_f32_16x16x32_bf16(ah[1][k], bl, acc[1][ct], 0, 0, 0);
        }
    }

#pragma unroll
    for (int rt = 0; rt < 2; rt++) {
        int rb = r0 + rt * 16 + q * 4;
#pragma unroll
        for (int reg = 0; reg < 4; reg++) {
            int row = rb + reg;
            if (row < n) {
#pragma unroll
                for (int ct = 0; ct < 8; ct++)
                    outp[(size_t)row * 128 + ct * 16 + m] =
                        __float2half(acc[rt][ct][reg]);
            }
        }
    }
}

// ------- K1: coarse count (both keys) + W transpose/split, one dispatch -----
__global__ __launch_bounds__(256) void count_split(
    const int* __restrict__ src, const int* __restrict__ dst,
    int* __restrict__ partialS, int* __restrict__ partialD,
    const float* __restrict__ W0, const float* __restrict__ W1,
    const float* __restrict__ W2,
    unsigned short* __restrict__ W0th, unsigned short* __restrict__ W0tl,
    unsigned short* __restrict__ W1th, unsigned short* __restrict__ W1tl,
    unsigned short* __restrict__ W2th, unsigned short* __restrict__ W2tl,
    int ne, int chunkA, int C, int NB)
{
    __shared__ int hS[256];
    __shared__ int hD[256];
    int bid = blockIdx.x, t = threadIdx.x;
    if (bid < C) {
        if (t < NB) { hS[t] = 0; hD[t] = 0; }
        __syncthreads();
        int e0 = bid * chunkA, e1 = min(ne, e0 + chunkA);
        for (int e = e0 + t; e < e1; e += 256) {
            atomicAdd(&hS[src[e] >> RBSHIFT], 1);
            atomicAdd(&hD[dst[e] >> RBSHIFT], 1);
        }
        __syncthreads();
        for (int i = t; i < NB; i += 256) {
            partialS[i * C + bid] = hS[i];
            partialD[i * C + bid] = hD[i];
        }
    } else {
        int e = (bid - C) * 256 + t;
        const float* W; unsigned short *Wh, *Wl; int NC, idx;
        bool ok = true;
        if (e < 16384)      { W = W0; Wh = W0th; Wl = W0tl; NC = 128; idx = e; }
        else if (e < 32768) { W = W1; Wh = W1th; Wl = W1tl; NC = 128; idx = e - 16384; }
        else if (e < 40960) { W = W2; Wh = W2th; Wl = W2tl; NC = 64;  idx = e - 32768; }
        else ok = false;
        if (ok) {
            int c = idx >> 7, kk = idx & 127;
            float w = W[kk * NC + c];
            unsigned short h = bf16_rne(w);
            Wh[idx] = h;
            Wl[idx] = bf16_rne(w - bf16_f(h));
        }
    }
}

// ------- K2: per-bucket prefix over chunks (1D) + fused GEMM-L0 tail --------
__global__ __launch_bounds__(256) void bucket_prefix(
    int* __restrict__ partialS, int* __restrict__ partialD,
    int* __restrict__ totS, int* __restrict__ totD, int C, int NB,
    const float* __restrict__ Xf, const unsigned short* __restrict__ W0th,
    const unsigned short* __restrict__ W0tl, __half* __restrict__ Th, int n)
{
    __shared__ int sh[256];
    int bid = blockIdx.x, t = threadIdx.x;
    if (bid >= 2 * NB) {
        gemm0_block(bid - 2 * NB, Xf, W0th, W0tl, Th, n);
        return;
    }
    int b = bid >> 1;
    int* part = (bid & 1) ? partialD : partialS;
    int* tot = (bid & 1) ? totD : totS;
    int v = (t < C) ? part[b * C + t] : 0;
    sh[t] = v;
    __syncthreads();
    for (int off = 1; off < 256; off <<= 1) {
        int x = (t >= off) ? sh[t - off] : 0;
        __syncthreads();
        sh[t] += x;
        __syncthreads();
    }
    if (t < C) part[b * C + t] = sh[t] - v;
    if (t == 255) tot[b] = sh[255];
}

// ------- K3: coarse scatter + fused GEMM-L0 tail ----------------------------
__global__ __launch_bounds__(256) void bucket_scatter(
    const int* __restrict__ src, const int* __restrict__ dst,
    const int* __restrict__ partialS, const int* __restrict__ partialD,
    const int* __restrict__ totS, const int* __restrict__ totD,
    unsigned short* __restrict__ src_bkt, int* __restrict__ edge_bkt,
    int ne, int chunkA, int C, int NB,
    const float* __restrict__ Xf, const unsigned short* __restrict__ W0th,
    const unsigned short* __restrict__ W0tl, __half* __restrict__ Th,
    int n, int G1)
{
    __shared__ int shB[256];
    __shared__ int curS[256];
    __shared__ int curD[256];
    int bid = blockIdx.x, t = threadIdx.x;
    if (bid >= C) {
        gemm0_block(bid - C + G1, Xf, W0th, W0tl, Th, n);
        return;
    }
    int vS = (t < NB) ? totS[t] : 0;
    shB[t] = vS;
    __syncthreads();
    for (int off = 1; off < 256; off <<= 1) {
        int x = (t >= off) ? shB[t - off] : 0;
        __syncthreads();
        shB[t] += x;
        __syncthreads();
    }
    if (t < NB) curS[t] = (shB[t] - vS) + partialS[t * C + bid];
    __syncthreads();
    int vD = (t < NB) ? totD[t] : 0;
    shB[t] = vD;
    __syncthreads();
    for (int off = 1; off < 256; off <<= 1) {
        int x = (t >= off) ? shB[t - off] : 0;
        __syncthreads();
        shB[t] += x;
        __syncthreads();
    }
    if (t < NB) curD[t] = (shB[t] - vD) + partialD[t * C + bid];
    __syncthreads();
    int e0 = bid * chunkA, e1 = min(ne, e0 + chunkA);
    for (int e = e0 + t; e < e1; e += 256) {
        int s = src[e];
        int d = dst[e];
        int posD = atomicAdd(&curD[d >> RBSHIFT], 1);
        edge_bkt[posD] = ((d & (RB - 1)) << 17) | s;
        int posS = atomicAdd(&curS[s >> RBSHIFT], 1);
        src_bkt[posS] = (unsigned short)(s & (RB - 1));
    }
}

// ------- K4: fine pass + fused GEMM-L0 tail ---------------------------------
// bid even (y=0): dst — hist+scan -> row_off/norm_dst + csr scatter
// bid odd  (y=1): src — hist -> norm_src
__global__ __launch_bounds__(256) void fine_all(
    const int* __restrict__ edge_bkt, const unsigned short* __restrict__ src_bkt,
    const int* __restrict__ totS, const int* __restrict__ totD,
    int* __restrict__ row_off, float* __restrict__ norm_dst,
    float* __restrict__ norm_src, int* __restrict__ csr, int n, int ne, int NB,
    const float* __restrict__ Xf, const unsigned short* __restrict__ W0th,
    const unsigned short* __restrict__ W0tl, __half* __restrict__ Th, int G12)
{
    __shared__ int shA[RB];     // hist + cursors
    __shared__ int shB[256];    // scans
    int bid = blockIdx.x, t = threadIdx.x;
    if (bid >= 2 * NB) {
        gemm0_block(bid - 2 * NB + G12, Xf, W0th, W0tl, Th, n);
        return;
    }
    int y = bid & 1, b = bid >> 1;
    const int* tot = y ? totS : totD;
    int v = (t < NB) ? tot[t] : 0;
    shB[t] = v;
    __syncthreads();
    for (int off = 1; off < 256; off <<= 1) {
        int x = (t >= off) ? shB[t - off] : 0;
        __syncthreads();
        shB[t] += x;
        __syncthreads();
    }
    int e1 = shB[b];           // inclusive scan at b = exclusive end
    int ebase = e1 - tot[b];   // exclusive start
    __syncthreads();
    int lo = b << RBSHIFT;
    for (int i = t; i < RB; i += 256) shA[i] = 0;
    __syncthreads();
    if (y == 1) {
        for (int e = ebase + t; e < e1; e += 256)
            atomicAdd(&shA[src_bkt[e]], 1);
        __syncthreads();
        for (int i = t; i < RB; i += 256) {
            int g = lo + i;
            if (g < n) norm_src[g] = rsqrtf((float)max(shA[i], 1));
        }
        return;
    }
    if (bid == 0 && t == 0) row_off[n] = ne;
    for (int e = ebase + t; e < e1; e += 256)
        atomicAdd(&shA[(unsigned)edge_bkt[e] >> 17], 1);
    __syncthreads();
    int v0 = shA[2 * t], v1 = shA[2 * t + 1];
    shB[t] = v0 + v1;
    __syncthreads();
    for (int off = 1; off < 256; off <<= 1) {
        int x = (t >= off) ? shB[t - off] : 0;
        __syncthreads();
        shB[t] += x;
        __syncthreads();
    }
    int excl = shB[t] - (v0 + v1) + ebase;
    int g0 = lo + 2 * t, g1 = g0 + 1;
    if (g0 < n) { row_off[g0] = excl;      norm_dst[g0] = rsqrtf((float)max(v0, 1)); }
    if (g1 < n) { row_off[g1] = excl + v0; norm_dst[g1] = rsqrtf((float)max(v1, 1)); }
    shA[2 * t] = excl;          // cursors
    shA[2 * t + 1] = excl + v0;
    __syncthreads();
    for (int e = ebase + t; e < e1; e += 256) {
        int p = edge_bkt[e];
        int pos = atomicAdd(&shA[(unsigned)p >> 17], 1);
        csr[pos] = p & 0x1FFFF;
    }
}

// ---------------- MFMA GEMM (layers 1-2): out = scale ⊙ (X @ W) -------------
// MODE 1: X16 fp16 [n_pad][128] (exact trunc split). W staged in LDS.
template <int NCOL, bool HALF_OUT, int MODE>
__global__ __launch_bounds__(256) void gemm_mfma(
    const __half* __restrict__ X16, const float* __restrict__ Xf,
    const unsigned short* __restrict__ Wth, const unsigned short* __restrict__ Wtl,
    const float* __restrict__ scale, void* __restrict__ outv, int n)
{
    constexpr int CT = NCOL / 16;
    constexpr int CHUNKS = NCOL * 16;          // 16B chunks per half
    __shared__ unsigned short Ws[16 * NCOL * 8];  // [sec][col^(sec&7)][8]

    int t = threadIdx.x;
    int w = t >> 6, lane = t & 63, m = lane & 15, q = lane >> 4;
    int r0 = blockIdx.x * 128 + w * 32;

    f32x4 acc[2][CT];
#pragma unroll
    for (int i = 0; i < 2; i++)
#pragma unroll
        for (int j = 0; j < CT; j++) acc[i][j] = (f32x4){0.f, 0.f, 0.f, 0.f};

    bf16x8 ah[2][4], al[2][4];
#pragma unroll
    for (int rt = 0; rt < 2; rt++) {
        int row = r0 + rt * 16 + m;
        size_t base = (size_t)row * K_FEATS + q * 8;
#pragma unroll
        for (int k = 0; k < 4; k++) {
            float f[8];
            if (MODE == 0) {
                if (row < n) {
                    *(float4*)&f[0] = *(const float4*)(Xf + base + k * 32);
                    *(float4*)&f[4] = *(const float4*)(Xf + base + k * 32 + 4);
                } else {
#pragma unroll
                    for (int j = 0; j < 8; j++) f[j] = 0.f;
                }
            } else {
                union { uint4 q4; __half h[8]; } U;
                U.q4 = *(const uint4*)(X16 + base + k * 32);
#pragma unroll
                for (int j = 0; j < 8; j++) f[j] = __half2float(U.h[j]);
            }
            union { bf16x8 v; unsigned short u[8]; } H, L;
#pragma unroll
            for (int j = 0; j < 8; j++) {
                unsigned uf = __float_as_uint(f[j]);
                H.u[j] = (unsigned short)(uf >> 16);                 // trunc hi
                float r = f[j] - __uint_as_float(uf & 0xFFFF0000u);  // exact
                if (MODE == 1)
                    L.u[j] = (unsigned short)(__float_as_uint(r) >> 16); // exact
                else
                    L.u[j] = bf16_rne(r);
            }
            ah[rt][k] = H.v;
            al[rt][k] = L.v;
        }
    }

#pragma unroll
    for (int i = 0; i < CHUNKS / 256; i++) {
        int g = t + i * 256;
        int col = g >> 4, sec = g & 15;
        *(bf16x8*)(Ws + sec * NCOL * 8 + ((col ^ (sec & 7)) * 8)) =
            *(const bf16x8*)(Wth + g * 8);
    }
    __syncthreads();
#pragma unroll
    for (int k = 0; k < 4; k++) {
        int sec = k * 4 + q;
#pragma unroll
        for (int ct = 0; ct < CT; ct++) {
            bf16x8 bh = *(const bf16x8*)(Ws + sec * NCOL * 8 +
                                         (((ct * 16 + m) ^ (sec & 7)) * 8));
            acc[0][ct] = __builtin_amdgcn_mfma_f32_16x16x32_bf16(ah[0][k], bh, acc[0][ct], 0, 0, 0);
            acc[0][ct] = __builtin_amdgcn_mfma_f32_16x16x32_bf16(al[0][k], bh, acc[0][ct], 0, 0, 0);
            acc[1][ct] = __builtin_amdgcn_mfma_f32_16x16x32_bf16(ah[1][k], bh, acc[1][ct], 0, 0, 0);
            acc[1][ct] = __builtin_amdgcn_mfma_f32_16x16x32_bf16(al[1][k], bh, acc[1][ct], 0, 0, 0);
        }
    }
    __syncthreads();
#pragma unroll
    for (int i = 0; i < CHUNKS / 256; i++) {
        int g = t + i * 256;
        int col = g >> 4, sec = g & 15;
        *(bf16x8*)(Ws + sec * NCOL * 8 + ((col ^ (sec & 7)) * 8)) =
            *(const bf16x8*)(Wtl + g * 8);
    }
    __syncthreads();
#pragma unroll
    for (int k = 0; k < 4; k++) {
        int sec = k * 4 + q;
#pragma unroll
        for (int ct = 0; ct < CT; ct++) {
            bf16x8 bl = *(const bf16x8*)(Ws + sec * NCOL * 8 +
                                         (((ct * 16 + m) ^ (sec & 7)) * 8));
            acc[0][ct] = __builtin_amdgcn_mfma_f32_16x16x32_bf16(ah[0][k], bl, acc[0][ct], 0, 0, 0);
            acc[1][ct] = __builtin_amdgcn_mfma_f32_16x16x32_bf16(ah[1][k], bl, acc[1][ct], 0, 0, 0);
        }
    }

#pragma unroll
    for (int rt = 0; rt < 2; rt++) {
        int rb = r0 + rt * 16 + q * 4;
#pragma unroll
        for (int reg = 0; reg < 4; reg++) {
            int row = rb + reg;
            if (row < n) {
                float s = scale[row];
#pragma unroll
                for (int ct = 0; ct < CT; ct++) {
                    float v = acc[rt][ct][reg] * s;
                    size_t o = (size_t)row * NCOL + ct * 16 + m;
                    if (HALF_OUT) ((__half*)outv)[o] = __float2half(v);
                    else ((float*)outv)[o] = v;
                }
            }
        }
    }
}

// ---------------- fp16-gather aggregation (128 feats) -> fp16 out -----------
// 16-lane teams, 8 fp16 feats/lane, 4 edges in flight.
// NSRC: per-edge norm_src fma (layer 0, whose GEMM writes unscaled T0).
template <bool RELU, bool NSRC>
__global__ __launch_bounds__(256) void aggregate4h(
    const __half* __restrict__ Tm, const int* __restrict__ row_off,
    const int* __restrict__ csr, const float* __restrict__ ndst,
    const float* __restrict__ nsrc,
    const float* __restrict__ bias, __half* __restrict__ Oh, int n)
{
    int lane = threadIdx.x & 15;
    int team = threadIdx.x >> 4;
    int fb = lane * 8;
    float b[8];
    *(float4*)&b[0] = *(const float4*)(bias + fb);
    *(float4*)&b[4] = *(const float4*)(bias + fb + 4);
    int stride = gridDim.x * 16;
    for (int v = blockIdx.x * 16 + team; v < n; v += stride) {
        int s = row_off[v], e = row_off[v + 1];
        float nd = ndst[v];
        float a[8] = {};
        int i = s;
        for (; i + 4 <= e; i += 4) {
            int u0 = csr[i], u1 = csr[i + 1], u2 = csr[i + 2], u3 = csr[i + 3];
            union { uint4 q; __half h[8]; } U0, U1, U2, U3;
            U0.q = *(const uint4*)(Tm + (size_t)u0 * 128 + fb);
            U1.q = *(const uint4*)(Tm + (size_t)u1 * 128 + fb);
            U2.q = *(const uint4*)(Tm + (size_t)u2 * 128 + fb);
            U3.q = *(const uint4*)(Tm + (size_t)u3 * 128 + fb);
            if (NSRC) {
                float s0 = nsrc[u0], s1 = nsrc[u1], s2 = nsrc[u2], s3 = nsrc[u3];
#pragma unroll
                for (int j = 0; j < 8; j++)
                    a[j] += (s0 * __half2float(U0.h[j]) + s1 * __half2float(U1.h[j])) +
                            (s2 * __half2float(U2.h[j]) + s3 * __half2float(U3.h[j]));
            } else {
#pragma unroll
                for (int j = 0; j < 8; j++)
                    a[j] += (__half2float(U0.h[j]) + __half2float(U1.h[j])) +
                            (__half2float(U2.h[j]) + __half2float(U3.h[j]));
            }
        }
        for (; i < e; i++) {
            int u = csr[i];
            union { uint4 q; __half h[8]; } U;
            U.q = *(const uint4*)(Tm + (size_t)u * 128 + fb);
            if (NSRC) {
                float s0 = nsrc[u];
#pragma unroll
                for (int j = 0; j < 8; j++) a[j] += s0 * __half2float(U.h[j]);
            } else {
#pragma unroll
                for (int j = 0; j < 8; j++) a[j] += __half2float(U.h[j]);
            }
        }
        union { uint4 q; __half h[8]; } O;
#pragma unroll
        for (int j = 0; j < 8; j++) {
            float o = nd * a[j] + b[j];
            if (RELU) o = fmaxf(o, 0.f);
            O.h[j] = __float2half(o);
        }
        *(uint4*)(Oh + (size_t)v * 128 + fb) = O.q;
    }
}

// ------- final aggregation: fp16 T (64 feats), fp32 out, 8-lane teams -------
__global__ __launch_bounds__(256) void aggregate2h(
    const __half* __restrict__ Tm, const int* __restrict__ row_off,
    const int* __restrict__ csr, const float* __restrict__ ndst,
    const float* __restrict__ bias, float* __restrict__ out, int n)
{
    int lane = threadIdx.x & 7;
    int team = threadIdx.x >> 3;      // 32 teams/block
    int fb = lane * 8;
    float b[8];
    *(float4*)&b[0] = *(const float4*)(bias + fb);
    *(float4*)&b[4] = *(const float4*)(bias + fb + 4);
    int stride = gridDim.x * 32;
    for (int v = blockIdx.x * 32 + team; v < n; v += stride) {
        int s = row_off[v], e = row_off[v + 1];
        float nd = ndst[v];
        float a[8] = {};
        int i = s;
        for (; i + 4 <= e; i += 4) {
            int u0 = csr[i], u1 = csr[i + 1], u2 = csr[i + 2], u3 = csr[i + 3];
            union { uint4 q; __half h[8]; } U0, U1, U2, U3;
            U0.q = *(const uint4*)(Tm + (size_t)u0 * 64 + fb);
            U1.q = *(const uint4*)(Tm + (size_t)u1 * 64 + fb);
            U2.q = *(const uint4*)(Tm + (size_t)u2 * 64 + fb);
            U3.q = *(const uint4*)(Tm + (size_t)u3 * 64 + fb);
#pragma unroll
            for (int j = 0; j < 8; j++)
                a[j] += (__half2float(U0.h[j]) + __half2float(U1.h[j])) +
                        (__half2float(U2.h[j]) + __half2float(U3.h[j]));
        }
        for (; i < e; i++) {
            int u = csr[i];
            union { uint4 q; __half h[8]; } U;
            U.q = *(const uint4*)(Tm + (size_t)u * 64 + fb);
#pragma unroll
            for (int j = 0; j < 8; j++) a[j] += __half2float(U.h[j]);
        }
        float o[8];
#pragma unroll
        for (int j = 0; j < 8; j++) o[j] = nd * a[j] + b[j];
        *(float4*)(out + (size_t)v * 64 + fb) = *(float4*)&o[0];
        *(float4*)(out + (size_t)v * 64 + fb + 4) = *(float4*)&o[4];
    }
}

// ---------------- launch ----------------
extern "C" void kernel_launch(void* const* d_in, const int* in_sizes, int n_in,
                              void* d_out, int out_size, void* d_ws, size_t ws_size,
                              hipStream_t stream)
{
    const float* features = (const float*)d_in[0];
    const int* src = (const int*)d_in[1];
    const int* dst = (const int*)d_in[2];
    const float* W0 = (const float*)d_in[3];
    const float* b0 = (const float*)d_in[4];
    const float* W1 = (const float*)d_in[5];
    const float* b1 = (const float*)d_in[6];
    const float* W2 = (const float*)d_in[7];
    const float* b2 = (const float*)d_in[8];

    int n = in_sizes[0] / K_FEATS;  // 100000
    int ne = in_sizes[1];           // 1600000
    int n_pad = (n + 127) & ~127;   // 100096

    char* ws = (char*)d_ws;
    size_t off = 0;
    auto take = [&](size_t bytes) -> char* {
        char* p = ws + off;
        off = (off + bytes + 255) & ~(size_t)255;
        return p;
    };
    __half* Xbuf = (__half*)take((size_t)n_pad * 128 * 2);  // h (fp16) ping
    __half* Th = (__half*)take((size_t)n_pad * 128 * 2);    // T (fp16) pong
    int* csr = (int*)take((size_t)ne * 4);
    int* edge_bkt = (int*)take((size_t)ne * 4);
    unsigned short* src_bkt = (unsigned short*)take((size_t)ne * 2);
    int* row_off = (int*)take((size_t)(n + 1) * 4);
    float* norm_src = (float*)take((size_t)n * 4);
    float* norm_dst = (float*)take((size_t)n * 4);
    unsigned short* W0th = (unsigned short*)take(128 * 128 * 2);
    unsigned short* W0tl = (unsigned short*)take(128 * 128 * 2);
    unsigned short* W1th = (unsigned short*)take(128 * 128 * 2);
    unsigned short* W1tl = (unsigned short*)take(128 * 128 * 2);
    unsigned short* W2th = (unsigned short*)take(64 * 128 * 2);
    unsigned short* W2tl = (unsigned short*)take(64 * 128 * 2);

    int NB = (n + RB - 1) >> RBSHIFT;        // 196 (must be <= 256)
    int chunkA = 8192;
    int C = (ne + chunkA - 1) / chunkA;
    if (C > 256) { chunkA = (ne + 255) / 256; C = (ne + chunkA - 1) / chunkA; }

    int* partialS = (int*)take((size_t)NB * C * 4);
    int* partialD = (int*)take((size_t)NB * C * 4);
    int* totS = (int*)take((size_t)NB * 4);
    int* totD = (int*)take((size_t)NB * 4);

    int gblocks = n_pad / 128;               // 782 layer-0 GEMM blocks
    int G1 = 128;                            // GEMM tail in prefix dispatch
    int G2 = (gblocks - G1) / 2;             // tail in scatter
    int G3 = gblocks - G1 - G2;              // tail in fine

    // CSR build, with layer-0 GEMM blocks fused into the underfilled
    // dispatches (W0th/W0tl ready after count_split; no dependency on CSR).
    count_split<<<C + 160, 256, 0, stream>>>(
        src, dst, partialS, partialD,
        W0, W1, W2, W0th, W0tl, W1th, W1tl, W2th, W2tl,
        ne, chunkA, C, NB);
    bucket_prefix<<<2 * NB + G1, 256, 0, stream>>>(
        partialS, partialD, totS, totD, C, NB,
        features, W0th, W0tl, Th, n);
    bucket_scatter<<<C + G2, 256, 0, stream>>>(
        src, dst, partialS, partialD, totS, totD, src_bkt, edge_bkt,
        ne, chunkA, C, NB, features, W0th, W0tl, Th, n, G1);
    fine_all<<<2 * NB + G3, 256, 0, stream>>>(
        edge_bkt, src_bkt, totS, totD, row_off, norm_dst, norm_src, csr,
        n, ne, NB, features, W0th, W0tl, Th, G1 + G2);

    int ablocks4 = (n + 15) / 16;
    int ablocks2 = (n + 31) / 32;

    // layer 0 aggregation: T0 is unscaled, norm_src applied per-edge (fma)
    aggregate4h<true, true><<<ablocks4, 256, 0, stream>>>(
        Th, row_off, csr, norm_dst, norm_src, b0, Xbuf, n);
    // layer 1 (fp16 in, exact trunc split; scale in GEMM as before)
    gemm_mfma<128, true, 1><<<gblocks, 256, 0, stream>>>(
        Xbuf, nullptr, W1th, W1tl, norm_src, Th, n);
    aggregate4h<true, false><<<ablocks4, 256, 0, stream>>>(
        Th, row_off, csr, norm_dst, nullptr, b1, Xbuf, n);
    // layer 2 (NCOL=64, fp16 T, fp32 out, no relu)
    gemm_mfma<64, true, 1><<<gblocks, 256, 0, stream>>>(
        Xbuf, nullptr, W2th, W2tl, norm_src, Th, n);
    aggregate2h<<<ablocks2, 256, 0, stream>>>(Th, row_off, csr, norm_dst, b2,
                                              (float*)d_out, n);
}